// Round 6
// baseline (415.527 us; speedup 1.0000x reference)
//
#include <hip/hip_runtime.h>
#include <hip/hip_bf16.h>

#define T_SEQ 4096
#define DIM   256
#define NBATCH 4

typedef short s8v __attribute__((ext_vector_type(8)));   // 8 bf16 (A/B frag)
typedef float f4v __attribute__((ext_vector_type(4)));   // 4 fp32 (C/D frag)
typedef unsigned short u16;

#define MFMA16(a,b,c) __builtin_amdgcn_mfma_f32_16x16x32_bf16(a,b,c,0,0,0)
#define FENCE_LGKM() asm volatile("s_waitcnt lgkmcnt(0)" ::: "memory")

// dynamic task counters, one per batch; zeroed by wtrans_kernel each launch
__device__ int g_cnt[4];

static __device__ __forceinline__ u16 f2bf(float f) {
  union { float f; unsigned int u; } c; c.f = f;
  unsigned int u = c.u;
  unsigned int r = (u + 0x7fffu + ((u >> 16) & 1u)) >> 16;   // RNE
  return (u16)r;
}

// pack 8 consecutive fp32 -> 8 bf16 (A-frag source)
static __device__ __forceinline__ s8v pack8(const float* p) {
  float4 a = *(const float4*)p;
  float4 b = *(const float4*)(p + 4);
  s8v r;
  r[0] = (short)f2bf(a.x); r[1] = (short)f2bf(a.y);
  r[2] = (short)f2bf(a.z); r[3] = (short)f2bf(a.w);
  r[4] = (short)f2bf(b.x); r[5] = (short)f2bf(b.y);
  r[6] = (short)f2bf(b.z); r[7] = (short)f2bf(b.w);
  return r;
}

// ---------- diagnostic fallback (fp32 out) ----------
__global__ void diag_fill_kernel(float* __restrict__ out, float val, int n) {
  int i = blockIdx.x * blockDim.x + threadIdx.x;
  if (i < n) out[i] = val;
}

// ---------- kernel 1: Wt[n][k] = bf16(W[k][n]) for the 3 weight matrices ----------
__global__ void wtrans_kernel(const float* __restrict__ Wq, const float* __restrict__ Wk,
                              const float* __restrict__ Wv, u16* __restrict__ Wt) {
  if (blockIdx.x == 0 && blockIdx.y == 0 && blockIdx.z == 0 &&
      threadIdx.y == 0 && threadIdx.x < 4)
    g_cnt[threadIdx.x] = 0;                    // reset attn task queues (stream-ordered)
  __shared__ float tile[32][33];
  int m = blockIdx.z;
  const float* W = (m == 0) ? Wq : ((m == 1) ? Wk : Wv);
  int bx = blockIdx.x * 32, by = blockIdx.y * 32;
  int x = threadIdx.x, y = threadIdx.y;          // block (32,8)
  #pragma unroll
  for (int i = 0; i < 32; i += 8) tile[y + i][x] = W[(by + y + i) * DIM + bx + x];
  __syncthreads();
  u16* o = Wt + m * DIM * DIM;
  #pragma unroll
  for (int i = 0; i < 32; i += 8) o[(bx + y + i) * DIM + by + x] = f2bf(tile[x][y + i]);
}

// ---------- kernel 2: K / V^T projections -> FRAGMENT-MAJOR tile format ------
// (unchanged)
__global__ __launch_bounds__(256) void proj_kernel(
    const float* __restrict__ x, const u16* __restrict__ Wt,
    const float* __restrict__ bk, const float* __restrict__ bv,
    u16* __restrict__ kf, u16* __restrict__ vf) {
  alignas(16) __shared__ u16 Kl[64 * 264];       // K rows, pad 256->264
  alignas(16) __shared__ u16 Vl[256 * 72];       // V^T [c][t_local], pad 64->72

  int bid = blockIdx.x;
  int which = blockIdx.y;                        // 0 = K, 1 = V
  int tid  = threadIdx.x;
  int wave = tid >> 6, lane = tid & 63, quad = lane >> 4, l16 = lane & 15;
  int row0 = bid * 64 + wave * 16;

  s8v a[8];
  const float* xp = x + (size_t)(row0 + l16) * DIM + quad * 8;
  #pragma unroll
  for (int ks = 0; ks < 8; ks++) a[ks] = pack8(xp + ks * 32);

  if (which == 0) {
    const u16* W = Wt + DIM * DIM;               // Wk^T
    f4v acc[16];
    #pragma unroll
    for (int nt = 0; nt < 16; nt++) acc[nt] = (f4v){0.f, 0.f, 0.f, 0.f};
    #pragma unroll
    for (int ks = 0; ks < 8; ks++) {
      #pragma unroll
      for (int nt = 0; nt < 16; nt++) {
        s8v bfr = *(const s8v*)(W + (nt * 16 + l16) * DIM + ks * 32 + quad * 8);
        acc[nt] = MFMA16(a[ks], bfr, acc[nt]);
      }
    }
    #pragma unroll
    for (int nt = 0; nt < 16; nt++) {
      float bb = bk[nt * 16 + l16];
      #pragma unroll
      for (int r = 0; r < 4; r++)
        Kl[(wave * 16 + quad * 4 + r) * 264 + nt * 16 + l16] = f2bf(acc[nt][r] + bb);
    }
    __syncthreads();
    #pragma unroll
    for (int i = 0; i < 8; i++) {                // 2048 chunks, 8/thread
      int o = tid + i * 256;
      int tile = o >> 10, rem = o & 1023;
      int f = rem >> 6, ln = rem & 63;
      int sl = tile * 32 + (f >> 3) * 16 + (ln & 15);
      int c  = (f & 7) * 32 + (ln >> 4) * 8;
      s8v v = *(const s8v*)&Kl[sl * 264 + c];
      *(s8v*)&kf[(((size_t)(bid * 2 + tile) * 16 + f) * 64 + ln) * 8] = v;
    }
  } else {
    const u16* W = Wt + 2 * DIM * DIM;           // Wv^T
    f4v acc[16];
    #pragma unroll
    for (int nt = 0; nt < 16; nt++) acc[nt] = (f4v){0.f, 0.f, 0.f, 0.f};
    #pragma unroll
    for (int ks = 0; ks < 8; ks++) {
      #pragma unroll
      for (int nt = 0; nt < 16; nt++) {
        s8v bfr = *(const s8v*)(W + (nt * 16 + l16) * DIM + ks * 32 + quad * 8);
        acc[nt] = MFMA16(a[ks], bfr, acc[nt]);
      }
    }
    #pragma unroll
    for (int nt = 0; nt < 16; nt++) {
      float bb = bv[nt * 16 + l16];
      union { u16 h[4]; uint2 v2; } pk;
      #pragma unroll
      for (int r = 0; r < 4; r++) pk.h[r] = f2bf(acc[nt][r] + bb);
      *(uint2*)&Vl[(nt * 16 + l16) * 72 + wave * 16 + quad * 4] = pk.v2;
    }
    __syncthreads();
    #pragma unroll
    for (int i = 0; i < 8; i++) {                // 2048 chunks, 8/thread
      int o = tid + i * 256;
      int tile = o >> 10, rem = o & 1023;
      int nt = rem >> 6, ln = rem & 63;
      int c  = nt * 16 + (ln & 15);
      int sl = tile * 32 + (ln >> 4) * 8;
      s8v v = *(const s8v*)&Vl[c * 72 + sl];
      *(s8v*)&vf[(((size_t)(bid * 2 + tile) * 16 + nt) * 64 + ln) * 8] = v;
    }
  }
}

// ---------- kernel 3 v5: flash attn, LDS-shared K/V, chunked, NO atomics -----
// r5 LESSON: 16.7M fp32 atomicAdds = memory-side RMW across XCDs (WRITE_SIZE
// 440MB, 2x slowdown). Combine now via plain-store partials + separate combine
// kernel (kernel boundary = device coherence).
// Task = (b, q64 64-row tile, 32-kv-tile chunk): 160/batch, sizes <=32 iters
// (~uniform), dynamic descending. nchunks = (q64>>4)+1 in {1,2,3,4}.
// Single-chunk tiles: normalize + store out directly. Multi-chunk: write fp32
// partial O (64x256) + l (64) to compact slot; combine kernel sums+normalizes.
__global__ __launch_bounds__(256, 2) void attn_kernel(
    const float* __restrict__ x, const u16* __restrict__ wtq, const float* __restrict__ bq,
    const u16* __restrict__ kf, const u16* __restrict__ vf,
    float* __restrict__ Opart, float* __restrict__ lpart, float* __restrict__ out) {
  alignas(16) __shared__ u16 KV[2][16384];        // 64 KB: [buf][ K 8192 u16 | V 8192 u16 ]
  alignas(16) __shared__ u16 Ps[4 * 640];         // per-wave P staging, stride 40
  __shared__ int taskS;
  u16* Qs = &KV[0][0];                            // Q staging aliases KV (pre-loop only;
                                                  // stride-264 rows spill into KV[1] region,
                                                  // still inside the 32768-u16 block, dead
                                                  // before buf-1 staging begins)

  int bid = blockIdx.x;
  int b = bid & 3;
  int tid = threadIdx.x;
  int w = tid >> 6, lane = tid & 63, quad = lane >> 4, l16 = lane & 15;

  const u16* kfb = kf + (size_t)b * 128 * 8192;
  const u16* vfb = vf + (size_t)b * 128 * 8192;

  for (;;) {
    if (tid == 0) taskS = atomicAdd(&g_cnt[b], 1);
    __syncthreads();                              // also orders prev-task LDS reads
    int t = taskS;
    if (t >= 160) break;
    // descending-size enumeration: 16 q64's x4 chunks, x3, x2, x1
    int q64, c;
    if (t < 64)       { q64 = 63 - (t >> 2);        c = t & 3; }
    else if (t < 112) { int u = t - 64;  q64 = 47 - u / 3; c = u % 3; }
    else if (t < 144) { int u = t - 112; q64 = 31 - (u >> 1); c = u & 1; }
    else              { q64 = 15 - (t - 144);       c = 0; }
    int row0 = q64 * 64;
    int n = 2 * q64 + 2;                          // causal kv-tile count for this tile
    int lo = c * 32, hi = min(n, lo + 32);        // this chunk's kv range (never empty)
    int nch = (q64 >> 4) + 1;                     // total chunks for this tile

    // ---- Q projection: wave w computes cols [w*64, w*64+64) for ALL 64 rows,
    //      W-frags loaded once per (ks,j) and reused across the 4 slabs. ----
    {
      f4v qacc[4][4];
      #pragma unroll
      for (int g = 0; g < 4; g++)
        #pragma unroll
        for (int j = 0; j < 4; j++) qacc[g][j] = (f4v){0.f, 0.f, 0.f, 0.f};
      #pragma unroll
      for (int ks = 0; ks < 8; ks++) {
        s8v wf[4];
        #pragma unroll
        for (int j = 0; j < 4; j++)
          wf[j] = *(const s8v*)(wtq + ((w * 4 + j) * 16 + l16) * DIM + ks * 32 + quad * 8);
        #pragma unroll
        for (int g = 0; g < 4; g++) {
          s8v xa = pack8(x + (size_t)(b * T_SEQ + row0 + g * 16 + l16) * DIM + ks * 32 + quad * 8);
          #pragma unroll
          for (int j = 0; j < 4; j++) qacc[g][j] = MFMA16(xa, wf[j], qacc[g][j]);
        }
      }
      #pragma unroll
      for (int j = 0; j < 4; j++) {
        int nt = w * 4 + j;
        float bb = bq[nt * 16 + l16];
        #pragma unroll
        for (int g = 0; g < 4; g++)
          #pragma unroll
          for (int r = 0; r < 4; r++)
            Qs[(g * 16 + quad * 4 + r) * 264 + nt * 16 + l16] =
                f2bf((qacc[g][j][r] + bb) * 0.0625f);   // pre-scale 1/sqrt(256)
      }
    }
    __syncthreads();                              // Q staged (in KV region)
    s8v qa[8];
    #pragma unroll
    for (int ks = 0; ks < 8; ks++)
      qa[ks] = *(const s8v*)&Qs[(w * 16 + l16) * 264 + ks * 32 + quad * 8];
    __syncthreads();                              // all qa read before KV reuse

    int rowBase = row0 + w * 16;                  // wave = slab

    f4v o[16];
    #pragma unroll
    for (int nt = 0; nt < 16; nt++) o[nt] = (f4v){0.f, 0.f, 0.f, 0.f};
    float lrow[4] = {0.f, 0.f, 0.f, 0.f};

    // ---- prologue: stage tile lo into buf 0 (each wave stages 4KB K + 4KB V)
    uint4 st[8];
    {
      const u16* kp = kfb + ((size_t)lo << 13) + (w << 11) + (lane << 3);
      const u16* vp = vfb + ((size_t)lo << 13) + (w << 11) + (lane << 3);
      #pragma unroll
      for (int i = 0; i < 4; i++) {
        st[i]     = *(const uint4*)(kp + (i << 9));
        st[4 + i] = *(const uint4*)(vp + (i << 9));
      }
      u16* kd = &KV[0][(w << 11) + (lane << 3)];
      #pragma unroll
      for (int i = 0; i < 4; i++) {
        *(uint4*)(kd + (i << 9))        = st[i];
        *(uint4*)(kd + 8192 + (i << 9)) = st[4 + i];
      }
    }
    __syncthreads();

    #pragma unroll 1
    for (int kv = lo; kv < hi; kv++) {
      int cur = (kv - lo) & 1;
      bool more = (kv + 1 < hi);

      // issue next tile's global loads EARLY (latency hidden under compute)
      if (more) {
        const u16* kp = kfb + ((size_t)(kv + 1) << 13) + (w << 11) + (lane << 3);
        const u16* vp = vfb + ((size_t)(kv + 1) << 13) + (w << 11) + (lane << 3);
        #pragma unroll
        for (int i = 0; i < 4; i++) {
          st[i]     = *(const uint4*)(kp + (i << 9));
          st[4 + i] = *(const uint4*)(vp + (i << 9));
        }
      }

      // ---- consume buf[cur]: S = Q K^T ----
      f4v c0 = (f4v){0.f, 0.f, 0.f, 0.f}, c1 = (f4v){0.f, 0.f, 0.f, 0.f};
      {
        s8v kfr[8];
        #pragma unroll
        for (int f = 0; f < 8; f++) kfr[f] = *(const s8v*)&KV[cur][(f << 9) + (lane << 3)];
        #pragma unroll
        for (int ks = 0; ks < 8; ks++) c0 = MFMA16(qa[ks], kfr[ks], c0);
        #pragma unroll
        for (int f = 0; f < 8; f++) kfr[f] = *(const s8v*)&KV[cur][((8 + f) << 9) + (lane << 3)];
        #pragma unroll
        for (int ks = 0; ks < 8; ks++) c1 = MFMA16(qa[ks], kfr[ks], c1);
      }

      // p = exp(s); causal mask -> exact 0
      int s0 = kv * 32 + l16;
      #pragma unroll
      for (int r = 0; r < 4; r++) {
        int tq = rowBase + quad * 4 + r;
        float v0 = (s0 > tq)      ? -1e30f : c0[r];
        float v1 = (s0 + 16 > tq) ? -1e30f : c1[r];
        float p0 = __expf(v0);
        float p1 = __expf(v1);
        Ps[w * 640 + (quad * 4 + r) * 40 + l16]      = f2bf(p0);
        Ps[w * 640 + (quad * 4 + r) * 40 + 16 + l16] = f2bf(p1);
        lrow[r] += p0 + p1;
      }
      FENCE_LGKM();                               // Ps write->read (same wave)
      s8v pa = *(const s8v*)&Ps[w * 640 + l16 * 40 + quad * 8];

      // ---- PV from LDS V frags ----
      {
        s8v vfr[8];
        #pragma unroll
        for (int f = 0; f < 8; f++) vfr[f] = *(const s8v*)&KV[cur][8192 + (f << 9) + (lane << 3)];
        #pragma unroll
        for (int nt = 0; nt < 8; nt++) o[nt] = MFMA16(pa, vfr[nt], o[nt]);
        #pragma unroll
        for (int f = 0; f < 8; f++) vfr[f] = *(const s8v*)&KV[cur][8192 + ((8 + f) << 9) + (lane << 3)];
        #pragma unroll
        for (int nt = 0; nt < 8; nt++) o[8 + nt] = MFMA16(pa, vfr[nt], o[8 + nt]);
      }

      // write staged regs into the other buffer LATE (compiler waits vmcnt)
      if (more) {
        u16* kd = &KV[cur ^ 1][(w << 11) + (lane << 3)];
        #pragma unroll
        for (int i = 0; i < 4; i++) {
          *(uint4*)(kd + (i << 9))        = st[i];
          *(uint4*)(kd + 8192 + (i << 9)) = st[4 + i];
        }
      }
      __syncthreads();
    }

    // ---- epilogue: 16-lane row-sum reduce, then direct store or partial ----
    #pragma unroll
    for (int r = 0; r < 4; r++) {
      #pragma unroll
      for (int d = 1; d < 16; d <<= 1) lrow[r] += __shfl_xor(lrow[r], d);
    }

    if (nch == 1) {                               // full kv range done: normalize+store
      float inv[4];
      #pragma unroll
      for (int r = 0; r < 4; r++) inv[r] = 1.0f / lrow[r];
      #pragma unroll
      for (int nt = 0; nt < 16; nt++) {
        #pragma unroll
        for (int r = 0; r < 4; r++)
          out[(size_t)(b * T_SEQ + rowBase + quad * 4 + r) * DIM + nt * 16 + l16] =
              o[nt][r] * inv[r];
      }
    } else {                                      // write fp32 partial to compact slot
      int slotB = (q64 < 32) ? (q64 - 16) * 2
                : (q64 < 48) ? 32 + (q64 - 32) * 3
                             : 80 + (q64 - 48) * 4;
      int slot = b * 144 + slotB + c;
      float* Op = Opart + ((size_t)slot << 14);   // 64*256 floats per slot
      #pragma unroll
      for (int nt = 0; nt < 16; nt++) {
        #pragma unroll
        for (int r = 0; r < 4; r++)
          Op[(w * 16 + quad * 4 + r) * 256 + nt * 16 + l16] = o[nt][r];
      }
      if (l16 == 0) {
        #pragma unroll
        for (int r = 0; r < 4; r++)
          lpart[slot * 64 + w * 16 + quad * 4 + r] = lrow[r];
      }
    }
  }
}

// ---------- kernel 4: combine partials for multi-chunk tiles (q64 >= 16) -----
// grid 768 = 4 b x 48 q64 x 4 row-groups; block 256 (thread = column).
__global__ void combine_kernel(const float* __restrict__ Opart,
                               const float* __restrict__ lpart,
                               float* __restrict__ out) {
  int blk = blockIdx.x;
  int b = blk & 3;
  int rest = blk >> 2;                            // 0..191
  int q64 = 16 + (rest >> 2);
  int g = rest & 3;                               // 16-row group
  int col = threadIdx.x;
  int nch = (q64 >> 4) + 1;                       // 2,3,4
  int slotB = (q64 < 32) ? (q64 - 16) * 2
            : (q64 < 48) ? 32 + (q64 - 32) * 3
                         : 80 + (q64 - 48) * 4;
  int slot0 = b * 144 + slotB;
  #pragma unroll 4
  for (int i = 0; i < 16; i++) {
    int rt = g * 16 + i;                          // row within 64-row tile
    float acc = 0.f, ls = 0.f;
    for (int c = 0; c < nch; c++) {
      acc += Opart[(((size_t)(slot0 + c)) << 14) + rt * 256 + col];
      ls  += lpart[(slot0 + c) * 64 + rt];
    }
    out[(size_t)(b * T_SEQ + q64 * 64 + rt) * DIM + col] = acc / ls;
  }
}

extern "C" void kernel_launch(void* const* d_in, const int* in_sizes, int n_in,
                              void* d_out, int out_size, void* d_ws, size_t ws_size,
                              hipStream_t stream) {
  const float* x  = (const float*)d_in[0];
  const float* Wq = (const float*)d_in[1];
  const float* bq = (const float*)d_in[2];
  const float* Wk = (const float*)d_in[3];
  const float* bk = (const float*)d_in[4];
  const float* Wv = (const float*)d_in[5];
  const float* bv = (const float*)d_in[6];

  const size_t NTD = (size_t)NBATCH * T_SEQ * DIM;             // 4,194,304 elems
  const size_t WT_ELEMS = (size_t)3 * DIM * DIM;               //   196,608 elems
  const size_t NSLOT = 576;                                    // partial slots
  const size_t REQ_BYTES = (WT_ELEMS + 2 * NTD) * sizeof(u16)  // 17,170,432
                         + NSLOT * 16384 * sizeof(float)       // 37,748,736 Opart
                         + NSLOT * 64 * sizeof(float);         //    147,456 lpart

  if (ws_size < REQ_BYTES) {
    float val = (float)(ws_size >> 20);   // diagnostic: absmax encodes ws MiB
    diag_fill_kernel<<<(out_size + 255) / 256, 256, 0, stream>>>((float*)d_out, val, out_size);
    return;
  }

  u16* ws = (u16*)d_ws;
  u16* WT = ws;                    // [0]=Wq^T [1]=Wk^T [2]=Wv^T, 384 KiB
  u16* Kf = ws + WT_ELEMS;         // 8 MiB, frag-major K tiles
  u16* Vf = Kf + NTD;              // 8 MiB, frag-major V^T tiles
  float* Opart = (float*)(Vf + NTD);               // 36 MiB fp32 partial O
  float* lpart = Opart + NSLOT * 16384;            // 144 KiB fp32 partial l

  const int nOut = NBATCH * T_SEQ * DIM;

  wtrans_kernel<<<dim3(8, 8, 3), dim3(32, 8, 1), 0, stream>>>(Wq, Wk, Wv, WT);
  proj_kernel<<<dim3(256, 2, 1), dim3(256, 1, 1), 0, stream>>>(x, WT, bk, bv, Kf, Vf);
  attn_kernel<<<dim3(512, 1, 1), dim3(256, 1, 1), 0, stream>>>(x, WT, bq, Kf, Vf,
                                                               Opart, lpart, (float*)d_out);
  combine_kernel<<<dim3(768, 1, 1), dim3(256, 1, 1), 0, stream>>>(Opart, lpart, (float*)d_out);
  (void)nOut;
}

// Round 7
// 241.987 us; speedup vs baseline: 1.7171x; 1.7171x over previous
//
#include <hip/hip_runtime.h>
#include <hip/hip_bf16.h>

#define T_SEQ 4096
#define DIM   256
#define NBATCH 4

typedef short s8v __attribute__((ext_vector_type(8)));   // 8 bf16 (A/B frag)
typedef float f4v __attribute__((ext_vector_type(4)));   // 4 fp32 (C/D frag)
typedef unsigned short u16;

#define MFMA16(a,b,c) __builtin_amdgcn_mfma_f32_16x16x32_bf16(a,b,c,0,0,0)
#define FENCE_LGKM() asm volatile("s_waitcnt lgkmcnt(0)" ::: "memory")

// dynamic task counters, one per batch; zeroed by wtrans_kernel each launch
__device__ int g_cnt[4];

static __device__ __forceinline__ u16 f2bf(float f) {
  union { float f; unsigned int u; } c; c.f = f;
  unsigned int u = c.u;
  unsigned int r = (u + 0x7fffu + ((u >> 16) & 1u)) >> 16;   // RNE
  return (u16)r;
}

// pack 8 consecutive fp32 -> 8 bf16 (A-frag source)
static __device__ __forceinline__ s8v pack8(const float* p) {
  float4 a = *(const float4*)p;
  float4 b = *(const float4*)(p + 4);
  s8v r;
  r[0] = (short)f2bf(a.x); r[1] = (short)f2bf(a.y);
  r[2] = (short)f2bf(a.z); r[3] = (short)f2bf(a.w);
  r[4] = (short)f2bf(b.x); r[5] = (short)f2bf(b.y);
  r[6] = (short)f2bf(b.z); r[7] = (short)f2bf(b.w);
  return r;
}

// async global->LDS DMA, 16B/lane: lds dest is WAVE-UNIFORM base (+lane*16 by HW)
static __device__ __forceinline__ void gll16(const u16* g, u16* l) {
  __builtin_amdgcn_global_load_lds(
      (const __attribute__((address_space(1))) unsigned int*)g,
      (__attribute__((address_space(3))) unsigned int*)l, 16, 0, 0);
}

// ---------- diagnostic fallback (fp32 out) ----------
__global__ void diag_fill_kernel(float* __restrict__ out, float val, int n) {
  int i = blockIdx.x * blockDim.x + threadIdx.x;
  if (i < n) out[i] = val;
}

// ---------- kernel 1: Wt[n][k] = bf16(W[k][n]) for the 3 weight matrices ----------
__global__ void wtrans_kernel(const float* __restrict__ Wq, const float* __restrict__ Wk,
                              const float* __restrict__ Wv, u16* __restrict__ Wt) {
  if (blockIdx.x == 0 && blockIdx.y == 0 && blockIdx.z == 0 &&
      threadIdx.y == 0 && threadIdx.x < 4)
    g_cnt[threadIdx.x] = 0;                    // reset attn task queues (stream-ordered)
  __shared__ float tile[32][33];
  int m = blockIdx.z;
  const float* W = (m == 0) ? Wq : ((m == 1) ? Wk : Wv);
  int bx = blockIdx.x * 32, by = blockIdx.y * 32;
  int x = threadIdx.x, y = threadIdx.y;          // block (32,8)
  #pragma unroll
  for (int i = 0; i < 32; i += 8) tile[y + i][x] = W[(by + y + i) * DIM + bx + x];
  __syncthreads();
  u16* o = Wt + m * DIM * DIM;
  #pragma unroll
  for (int i = 0; i < 32; i += 8) o[(bx + y + i) * DIM + by + x] = f2bf(tile[x][y + i]);
}

// ---------- kernel 2: K / V^T projections -> FRAGMENT-MAJOR tile format ------
// (unchanged)
__global__ __launch_bounds__(256) void proj_kernel(
    const float* __restrict__ x, const u16* __restrict__ Wt,
    const float* __restrict__ bk, const float* __restrict__ bv,
    u16* __restrict__ kf, u16* __restrict__ vf) {
  alignas(16) __shared__ u16 Kl[64 * 264];       // K rows, pad 256->264
  alignas(16) __shared__ u16 Vl[256 * 72];       // V^T [c][t_local], pad 64->72

  int bid = blockIdx.x;
  int which = blockIdx.y;                        // 0 = K, 1 = V
  int tid  = threadIdx.x;
  int wave = tid >> 6, lane = tid & 63, quad = lane >> 4, l16 = lane & 15;
  int row0 = bid * 64 + wave * 16;

  s8v a[8];
  const float* xp = x + (size_t)(row0 + l16) * DIM + quad * 8;
  #pragma unroll
  for (int ks = 0; ks < 8; ks++) a[ks] = pack8(xp + ks * 32);

  if (which == 0) {
    const u16* W = Wt + DIM * DIM;               // Wk^T
    f4v acc[16];
    #pragma unroll
    for (int nt = 0; nt < 16; nt++) acc[nt] = (f4v){0.f, 0.f, 0.f, 0.f};
    #pragma unroll
    for (int ks = 0; ks < 8; ks++) {
      #pragma unroll
      for (int nt = 0; nt < 16; nt++) {
        s8v bfr = *(const s8v*)(W + (nt * 16 + l16) * DIM + ks * 32 + quad * 8);
        acc[nt] = MFMA16(a[ks], bfr, acc[nt]);
      }
    }
    #pragma unroll
    for (int nt = 0; nt < 16; nt++) {
      float bb = bk[nt * 16 + l16];
      #pragma unroll
      for (int r = 0; r < 4; r++)
        Kl[(wave * 16 + quad * 4 + r) * 264 + nt * 16 + l16] = f2bf(acc[nt][r] + bb);
    }
    __syncthreads();
    #pragma unroll
    for (int i = 0; i < 8; i++) {                // 2048 chunks, 8/thread
      int o = tid + i * 256;
      int tile = o >> 10, rem = o & 1023;
      int f = rem >> 6, ln = rem & 63;
      int sl = tile * 32 + (f >> 3) * 16 + (ln & 15);
      int c  = (f & 7) * 32 + (ln >> 4) * 8;
      s8v v = *(const s8v*)&Kl[sl * 264 + c];
      *(s8v*)&kf[(((size_t)(bid * 2 + tile) * 16 + f) * 64 + ln) * 8] = v;
    }
  } else {
    const u16* W = Wt + 2 * DIM * DIM;           // Wv^T
    f4v acc[16];
    #pragma unroll
    for (int nt = 0; nt < 16; nt++) acc[nt] = (f4v){0.f, 0.f, 0.f, 0.f};
    #pragma unroll
    for (int ks = 0; ks < 8; ks++) {
      #pragma unroll
      for (int nt = 0; nt < 16; nt++) {
        s8v bfr = *(const s8v*)(W + (nt * 16 + l16) * DIM + ks * 32 + quad * 8);
        acc[nt] = MFMA16(a[ks], bfr, acc[nt]);
      }
    }
    #pragma unroll
    for (int nt = 0; nt < 16; nt++) {
      float bb = bv[nt * 16 + l16];
      union { u16 h[4]; uint2 v2; } pk;
      #pragma unroll
      for (int r = 0; r < 4; r++) pk.h[r] = f2bf(acc[nt][r] + bb);
      *(uint2*)&Vl[(nt * 16 + l16) * 72 + wave * 16 + quad * 4] = pk.v2;
    }
    __syncthreads();
    #pragma unroll
    for (int i = 0; i < 8; i++) {                // 2048 chunks, 8/thread
      int o = tid + i * 256;
      int tile = o >> 10, rem = o & 1023;
      int nt = rem >> 6, ln = rem & 63;
      int c  = nt * 16 + (ln & 15);
      int sl = tile * 32 + (ln >> 4) * 8;
      s8v v = *(const s8v*)&Vl[c * 72 + sl];
      *(s8v*)&vf[(((size_t)(bid * 2 + tile) * 16 + nt) * 64 + ln) * 8] = v;
    }
  }
}

// ---------- kernel 3 v6: flash attn, global_load_lds staging, chunked --------
// r6 LESSON: uint4 st[8] reg-staging generated ~333MB of phantom HBM writes
// (scratch-spill stores; reloads L2-hit but dirty lines evicted by the K/V
// stream -> WRITE_SIZE 375MB, attn 298us). FIX: stage via async
// global_load_lds DMA (zero registers, zero ds_writes, linear LDS dest).
// Also: TRUE size-descending task order (r6 had 32-iter tasks in the tail).
__global__ __launch_bounds__(256, 2) void attn_kernel(
    const float* __restrict__ x, const u16* __restrict__ wtq, const float* __restrict__ bq,
    const u16* __restrict__ kf, const u16* __restrict__ vf,
    float* __restrict__ Opart, float* __restrict__ lpart, float* __restrict__ out) {
  alignas(16) __shared__ u16 KV[2][16384];        // 64 KB: [buf][ K 8192 u16 | V 8192 u16 ]
  alignas(16) __shared__ u16 Ps[4 * 640];         // per-wave P staging, stride 40
  __shared__ int taskS;
  u16* Qs = &KV[0][0];                            // Q staging aliases KV (pre-loop only;
                                                  // stride-264 rows spill into KV[1] region,
                                                  // still inside the 32768-u16 block, dead
                                                  // before staging begins)

  int bid = blockIdx.x;
  int b = bid & 3;                                // batch <-> XCD-pair affinity
  int tid = threadIdx.x;
  int w = tid >> 6, lane = tid & 63, quad = lane >> 4, l16 = lane & 15;

  const u16* kfb = kf + (size_t)b * 128 * 8192;
  const u16* vfb = vf + (size_t)b * 128 * 8192;

  for (;;) {
    if (tid == 0) taskS = atomicAdd(&g_cnt[b], 1);
    __syncthreads();                              // also orders prev-task LDS reads
    int t = taskS;
    if (t >= 160) break;
    // TRUE size-descending enumeration: 100 full 32-chunks (q64 desc), then 60
    // remainder chunks sizes 30,30,30,30,28,...,2 (4 of each size).
    int q64, c;
    if (t < 4)        { q64 = 63; c = t; }
    else if (t < 49)  { int u = t - 4;  q64 = 62 - u / 3; c = u % 3; }
    else if (t < 52)  { q64 = 47; c = t - 49; }
    else if (t < 82)  { int u = t - 52; q64 = 46 - (u >> 1); c = u & 1; }
    else if (t < 84)  { q64 = 31; c = t - 82; }
    else if (t < 99)  { q64 = 30 - (t - 84); c = 0; }
    else if (t == 99) { q64 = 15; c = 0; }
    else { int u = t - 100; int m = u >> 2, g = u & 3, j = 14 - m;
           if (g == 0)      { q64 = 16 + j; c = 1; }
           else if (g == 1) { q64 = 32 + j; c = 2; }
           else if (g == 2) { q64 = 48 + j; c = 3; }
           else             { q64 = j;      c = 0; } }
    int row0 = q64 * 64;
    int n = 2 * q64 + 2;                          // causal kv-tile count for this tile
    int lo = c * 32, hi = min(n, lo + 32);        // this chunk's kv range (never empty)
    int nch = (q64 >> 4) + 1;                     // total chunks for this tile

    // ---- Q projection: wave w computes cols [w*64, w*64+64) for ALL 64 rows,
    //      W-frags loaded once per (ks,j) and reused across the 4 slabs. ----
    {
      f4v qacc[4][4];
      #pragma unroll
      for (int g2 = 0; g2 < 4; g2++)
        #pragma unroll
        for (int j = 0; j < 4; j++) qacc[g2][j] = (f4v){0.f, 0.f, 0.f, 0.f};
      #pragma unroll
      for (int ks = 0; ks < 8; ks++) {
        s8v wf[4];
        #pragma unroll
        for (int j = 0; j < 4; j++)
          wf[j] = *(const s8v*)(wtq + ((w * 4 + j) * 16 + l16) * DIM + ks * 32 + quad * 8);
        #pragma unroll
        for (int g2 = 0; g2 < 4; g2++) {
          s8v xa = pack8(x + (size_t)(b * T_SEQ + row0 + g2 * 16 + l16) * DIM + ks * 32 + quad * 8);
          #pragma unroll
          for (int j = 0; j < 4; j++) qacc[g2][j] = MFMA16(xa, wf[j], qacc[g2][j]);
        }
      }
      #pragma unroll
      for (int j = 0; j < 4; j++) {
        int nt = w * 4 + j;
        float bb = bq[nt * 16 + l16];
        #pragma unroll
        for (int g2 = 0; g2 < 4; g2++)
          #pragma unroll
          for (int r = 0; r < 4; r++)
            Qs[(g2 * 16 + quad * 4 + r) * 264 + nt * 16 + l16] =
                f2bf((qacc[g2][j][r] + bb) * 0.0625f);   // pre-scale 1/sqrt(256)
      }
    }
    __syncthreads();                              // Q staged (in KV region)
    s8v qa[8];
    #pragma unroll
    for (int ks = 0; ks < 8; ks++)
      qa[ks] = *(const s8v*)&Qs[(w * 16 + l16) * 264 + ks * 32 + quad * 8];
    __syncthreads();                              // all qa read before KV DMA begins

    int rowBase = row0 + w * 16;                  // wave = slab

    f4v o[16];
    #pragma unroll
    for (int nt = 0; nt < 16; nt++) o[nt] = (f4v){0.f, 0.f, 0.f, 0.f};
    float lrow[4] = {0.f, 0.f, 0.f, 0.f};

    // ---- prologue: DMA tile lo into buf 0 (each wave: 4KB K + 4KB V, linear)
    {
      const u16* kt = kfb + ((size_t)lo << 13);
      const u16* vt = vfb + ((size_t)lo << 13);
      #pragma unroll
      for (int i = 0; i < 4; i++) {
        gll16(kt + (w << 11) + (i << 9) + (lane << 3), &KV[0][(w << 11) + (i << 9)]);
        gll16(vt + (w << 11) + (i << 9) + (lane << 3), &KV[0][8192 + (w << 11) + (i << 9)]);
      }
    }
    __syncthreads();                              // compiler drains vmcnt(0) here

    #pragma unroll 1
    for (int kv = lo; kv < hi; kv++) {
      int cur = (kv - lo) & 1;

      // issue next tile's DMA EARLY (async, lands in other buffer)
      if (kv + 1 < hi) {
        const u16* kt = kfb + ((size_t)(kv + 1) << 13);
        const u16* vt = vfb + ((size_t)(kv + 1) << 13);
        u16* dst = &KV[cur ^ 1][0];
        #pragma unroll
        for (int i = 0; i < 4; i++) {
          gll16(kt + (w << 11) + (i << 9) + (lane << 3), dst + (w << 11) + (i << 9));
          gll16(vt + (w << 11) + (i << 9) + (lane << 3), dst + 8192 + (w << 11) + (i << 9));
        }
      }

      // ---- consume buf[cur]: S = Q K^T ----
      f4v c0 = (f4v){0.f, 0.f, 0.f, 0.f}, c1 = (f4v){0.f, 0.f, 0.f, 0.f};
      {
        s8v kfr[8];
        #pragma unroll
        for (int f = 0; f < 8; f++) kfr[f] = *(const s8v*)&KV[cur][(f << 9) + (lane << 3)];
        #pragma unroll
        for (int ks = 0; ks < 8; ks++) c0 = MFMA16(qa[ks], kfr[ks], c0);
        #pragma unroll
        for (int f = 0; f < 8; f++) kfr[f] = *(const s8v*)&KV[cur][((8 + f) << 9) + (lane << 3)];
        #pragma unroll
        for (int ks = 0; ks < 8; ks++) c1 = MFMA16(qa[ks], kfr[ks], c1);
      }

      // p = exp(s); causal mask -> exact 0
      int s0 = kv * 32 + l16;
      #pragma unroll
      for (int r = 0; r < 4; r++) {
        int tq = rowBase + quad * 4 + r;
        float v0 = (s0 > tq)      ? -1e30f : c0[r];
        float v1 = (s0 + 16 > tq) ? -1e30f : c1[r];
        float p0 = __expf(v0);
        float p1 = __expf(v1);
        Ps[w * 640 + (quad * 4 + r) * 40 + l16]      = f2bf(p0);
        Ps[w * 640 + (quad * 4 + r) * 40 + 16 + l16] = f2bf(p1);
        lrow[r] += p0 + p1;
      }
      FENCE_LGKM();                               // Ps write->read (same wave)
      s8v pa = *(const s8v*)&Ps[w * 640 + l16 * 40 + quad * 8];

      // ---- PV from LDS V frags ----
      {
        s8v vfr[8];
        #pragma unroll
        for (int f = 0; f < 8; f++) vfr[f] = *(const s8v*)&KV[cur][8192 + (f << 9) + (lane << 3)];
        #pragma unroll
        for (int nt = 0; nt < 8; nt++) o[nt] = MFMA16(pa, vfr[nt], o[nt]);
        #pragma unroll
        for (int f = 0; f < 8; f++) vfr[f] = *(const s8v*)&KV[cur][8192 + ((8 + f) << 9) + (lane << 3)];
        #pragma unroll
        for (int nt = 0; nt < 8; nt++) o[8 + nt] = MFMA16(pa, vfr[nt], o[8 + nt]);
      }

      __syncthreads();                            // drains vmcnt -> next buf ready
    }

    // ---- epilogue: 16-lane row-sum reduce, then direct store or partial ----
    #pragma unroll
    for (int r = 0; r < 4; r++) {
      #pragma unroll
      for (int d = 1; d < 16; d <<= 1) lrow[r] += __shfl_xor(lrow[r], d);
    }

    if (nch == 1) {                               // full kv range done: normalize+store
      float inv[4];
      #pragma unroll
      for (int r = 0; r < 4; r++) inv[r] = 1.0f / lrow[r];
      #pragma unroll
      for (int nt = 0; nt < 16; nt++) {
        #pragma unroll
        for (int r = 0; r < 4; r++)
          out[(size_t)(b * T_SEQ + rowBase + quad * 4 + r) * DIM + nt * 16 + l16] =
              o[nt][r] * inv[r];
      }
    } else {                                      // write fp32 partial to compact slot
      int slotB = (q64 < 32) ? (q64 - 16) * 2
                : (q64 < 48) ? 32 + (q64 - 32) * 3
                             : 80 + (q64 - 48) * 4;
      int slot = b * 144 + slotB + c;
      float* Op = Opart + ((size_t)slot << 14);   // 64*256 floats per slot
      #pragma unroll
      for (int nt = 0; nt < 16; nt++) {
        #pragma unroll
        for (int r = 0; r < 4; r++)
          Op[(w * 16 + quad * 4 + r) * 256 + nt * 16 + l16] = o[nt][r];
      }
      if (l16 == 0) {
        #pragma unroll
        for (int r = 0; r < 4; r++)
          lpart[slot * 64 + w * 16 + quad * 4 + r] = lrow[r];
      }
    }
  }
}

// ---------- kernel 4: combine partials for multi-chunk tiles (q64 >= 16) -----
// grid 768 = 4 b x 48 q64 x 4 row-groups; block 256 (thread = column).
__global__ void combine_kernel(const float* __restrict__ Opart,
                               const float* __restrict__ lpart,
                               float* __restrict__ out) {
  int blk = blockIdx.x;
  int b = blk & 3;
  int rest = blk >> 2;                            // 0..191
  int q64 = 16 + (rest >> 2);
  int g = rest & 3;                               // 16-row group
  int col = threadIdx.x;
  int nch = (q64 >> 4) + 1;                       // 2,3,4
  int slotB = (q64 < 32) ? (q64 - 16) * 2
            : (q64 < 48) ? 32 + (q64 - 32) * 3
                         : 80 + (q64 - 48) * 4;
  int slot0 = b * 144 + slotB;
  #pragma unroll 4
  for (int i = 0; i < 16; i++) {
    int rt = g * 16 + i;                          // row within 64-row tile
    float acc = 0.f, ls = 0.f;
    for (int c = 0; c < nch; c++) {
      acc += Opart[(((size_t)(slot0 + c)) << 14) + rt * 256 + col];
      ls  += lpart[(slot0 + c) * 64 + rt];
    }
    out[(size_t)(b * T_SEQ + q64 * 64 + rt) * DIM + col] = acc / ls;
  }
}

extern "C" void kernel_launch(void* const* d_in, const int* in_sizes, int n_in,
                              void* d_out, int out_size, void* d_ws, size_t ws_size,
                              hipStream_t stream) {
  const float* x  = (const float*)d_in[0];
  const float* Wq = (const float*)d_in[1];
  const float* bq = (const float*)d_in[2];
  const float* Wk = (const float*)d_in[3];
  const float* bk = (const float*)d_in[4];
  const float* Wv = (const float*)d_in[5];
  const float* bv = (const float*)d_in[6];

  const size_t NTD = (size_t)NBATCH * T_SEQ * DIM;             // 4,194,304 elems
  const size_t WT_ELEMS = (size_t)3 * DIM * DIM;               //   196,608 elems
  const size_t NSLOT = 576;                                    // partial slots
  const size_t REQ_BYTES = (WT_ELEMS + 2 * NTD) * sizeof(u16)  // 17,170,432
                         + NSLOT * 16384 * sizeof(float)       // 37,748,736 Opart
                         + NSLOT * 64 * sizeof(float);         //    147,456 lpart

  if (ws_size < REQ_BYTES) {
    float val = (float)(ws_size >> 20);   // diagnostic: absmax encodes ws MiB
    diag_fill_kernel<<<(out_size + 255) / 256, 256, 0, stream>>>((float*)d_out, val, out_size);
    return;
  }

  u16* ws = (u16*)d_ws;
  u16* WT = ws;                    // [0]=Wq^T [1]=Wk^T [2]=Wv^T, 384 KiB
  u16* Kf = ws + WT_ELEMS;         // 8 MiB, frag-major K tiles
  u16* Vf = Kf + NTD;              // 8 MiB, frag-major V^T tiles
  float* Opart = (float*)(Vf + NTD);               // 36 MiB fp32 partial O
  float* lpart = Opart + NSLOT * 16384;            // 144 KiB fp32 partial l

  wtrans_kernel<<<dim3(8, 8, 3), dim3(32, 8, 1), 0, stream>>>(Wq, Wk, Wv, WT);
  proj_kernel<<<dim3(256, 2, 1), dim3(256, 1, 1), 0, stream>>>(x, WT, bk, bv, Kf, Vf);
  attn_kernel<<<dim3(512, 1, 1), dim3(256, 1, 1), 0, stream>>>(x, WT, bq, Kf, Vf,
                                                               Opart, lpart, (float*)d_out);
  combine_kernel<<<dim3(768, 1, 1), dim3(256, 1, 1), 0, stream>>>(Opart, lpart, (float*)d_out);
}

// Round 8
// 227.915 us; speedup vs baseline: 1.8232x; 1.0617x over previous
//
#include <hip/hip_runtime.h>
#include <hip/hip_bf16.h>

#define T_SEQ 4096
#define DIM   256
#define NBATCH 4

typedef short s8v __attribute__((ext_vector_type(8)));   // 8 bf16 (A/B frag)
typedef float f4v __attribute__((ext_vector_type(4)));   // 4 fp32 (C/D frag)
typedef unsigned short u16;

#define MFMA16(a,b,c) __builtin_amdgcn_mfma_f32_16x16x32_bf16(a,b,c,0,0,0)
#define FENCE_LGKM() asm volatile("s_waitcnt lgkmcnt(0)" ::: "memory")

// dynamic task counters, one per batch; zeroed by wtrans_kernel each launch
__device__ int g_cnt[4];

static __device__ __forceinline__ u16 f2bf(float f) {
  union { float f; unsigned int u; } c; c.f = f;
  unsigned int u = c.u;
  unsigned int r = (u + 0x7fffu + ((u >> 16) & 1u)) >> 16;   // RNE
  return (u16)r;
}

static __device__ __forceinline__ s8v pack8(const float* p) {
  float4 a = *(const float4*)p;
  float4 b = *(const float4*)(p + 4);
  s8v r;
  r[0] = (short)f2bf(a.x); r[1] = (short)f2bf(a.y);
  r[2] = (short)f2bf(a.z); r[3] = (short)f2bf(a.w);
  r[4] = (short)f2bf(b.x); r[5] = (short)f2bf(b.y);
  r[6] = (short)f2bf(b.z); r[7] = (short)f2bf(b.w);
  return r;
}

// async global->LDS DMA, 16B/lane: lds dest is WAVE-UNIFORM base (+lane*16 by HW)
static __device__ __forceinline__ void gll16(const u16* g, u16* l) {
  __builtin_amdgcn_global_load_lds(
      (const __attribute__((address_space(1))) unsigned int*)g,
      (__attribute__((address_space(3))) unsigned int*)l, 16, 0, 0);
}

// ---------- diagnostic fallback (fp32 out) ----------
__global__ void diag_fill_kernel(float* __restrict__ out, float val, int n) {
  int i = blockIdx.x * blockDim.x + threadIdx.x;
  if (i < n) out[i] = val;
}

// ---------- kernel 1: Wt[n][k] = bf16(W[k][n]) ----------
__global__ void wtrans_kernel(const float* __restrict__ Wq, const float* __restrict__ Wk,
                              const float* __restrict__ Wv, u16* __restrict__ Wt) {
  if (blockIdx.x == 0 && blockIdx.y == 0 && blockIdx.z == 0 &&
      threadIdx.y == 0 && threadIdx.x < 4)
    g_cnt[threadIdx.x] = 0;                    // reset attn task queues (stream-ordered)
  __shared__ float tile[32][33];
  int m = blockIdx.z;
  const float* W = (m == 0) ? Wq : ((m == 1) ? Wk : Wv);
  int bx = blockIdx.x * 32, by = blockIdx.y * 32;
  int x = threadIdx.x, y = threadIdx.y;          // block (32,8)
  #pragma unroll
  for (int i = 0; i < 32; i += 8) tile[y + i][x] = W[(by + y + i) * DIM + bx + x];
  __syncthreads();
  u16* o = Wt + m * DIM * DIM;
  #pragma unroll
  for (int i = 0; i < 32; i += 8) o[(bx + y + i) * DIM + by + x] = f2bf(tile[x][y + i]);
}

// ---------- kernel 2: Q / K / V projections ------
// grid (256, 3): y=0 -> K (frag-major), y=1 -> V^T (frag-major),
//                y=2 -> Q (row-major bf16, pre-scaled 1/16, bank-SWIZZLED:
//                          col' = (col + (row&31)*8) & 255, matching attn's qa read).
__global__ __launch_bounds__(256) void proj_kernel(
    const float* __restrict__ x, const u16* __restrict__ Wt,
    const float* __restrict__ bq, const float* __restrict__ bk, const float* __restrict__ bv,
    u16* __restrict__ qf, u16* __restrict__ kf, u16* __restrict__ vf) {
  alignas(16) __shared__ u16 Kl[64 * 264];       // rows, pad 256->264
  alignas(16) __shared__ u16 Vl[256 * 72];       // V^T [c][t_local], pad 64->72

  int bid = blockIdx.x;
  int which = blockIdx.y;                        // 0 = K, 1 = V, 2 = Q
  int tid  = threadIdx.x;
  int wave = tid >> 6, lane = tid & 63, quad = lane >> 4, l16 = lane & 15;
  int row0 = bid * 64 + wave * 16;

  s8v a[8];
  const float* xp = x + (size_t)(row0 + l16) * DIM + quad * 8;
  #pragma unroll
  for (int ks = 0; ks < 8; ks++) a[ks] = pack8(xp + ks * 32);

  if (which == 0) {
    const u16* W = Wt + DIM * DIM;               // Wk^T
    f4v acc[16];
    #pragma unroll
    for (int nt = 0; nt < 16; nt++) acc[nt] = (f4v){0.f, 0.f, 0.f, 0.f};
    #pragma unroll
    for (int ks = 0; ks < 8; ks++) {
      #pragma unroll
      for (int nt = 0; nt < 16; nt++) {
        s8v bfr = *(const s8v*)(W + (nt * 16 + l16) * DIM + ks * 32 + quad * 8);
        acc[nt] = MFMA16(a[ks], bfr, acc[nt]);
      }
    }
    #pragma unroll
    for (int nt = 0; nt < 16; nt++) {
      float bb = bk[nt * 16 + l16];
      #pragma unroll
      for (int r = 0; r < 4; r++)
        Kl[(wave * 16 + quad * 4 + r) * 264 + nt * 16 + l16] = f2bf(acc[nt][r] + bb);
    }
    __syncthreads();
    #pragma unroll
    for (int i = 0; i < 8; i++) {                // 2048 chunks, 8/thread
      int o = tid + i * 256;
      int tile = o >> 10, rem = o & 1023;
      int f = rem >> 6, ln = rem & 63;
      int sl = tile * 32 + (f >> 3) * 16 + (ln & 15);
      int c  = (f & 7) * 32 + (ln >> 4) * 8;
      s8v v = *(const s8v*)&Kl[sl * 264 + c];
      *(s8v*)&kf[(((size_t)(bid * 2 + tile) * 16 + f) * 64 + ln) * 8] = v;
    }
  } else if (which == 1) {
    const u16* W = Wt + 2 * DIM * DIM;           // Wv^T
    f4v acc[16];
    #pragma unroll
    for (int nt = 0; nt < 16; nt++) acc[nt] = (f4v){0.f, 0.f, 0.f, 0.f};
    #pragma unroll
    for (int ks = 0; ks < 8; ks++) {
      #pragma unroll
      for (int nt = 0; nt < 16; nt++) {
        s8v bfr = *(const s8v*)(W + (nt * 16 + l16) * DIM + ks * 32 + quad * 8);
        acc[nt] = MFMA16(a[ks], bfr, acc[nt]);
      }
    }
    #pragma unroll
    for (int nt = 0; nt < 16; nt++) {
      float bb = bv[nt * 16 + l16];
      union { u16 h[4]; uint2 v2; } pk;
      #pragma unroll
      for (int r = 0; r < 4; r++) pk.h[r] = f2bf(acc[nt][r] + bb);
      *(uint2*)&Vl[(nt * 16 + l16) * 72 + wave * 16 + quad * 4] = pk.v2;
    }
    __syncthreads();
    #pragma unroll
    for (int i = 0; i < 8; i++) {                // 2048 chunks, 8/thread
      int o = tid + i * 256;
      int tile = o >> 10, rem = o & 1023;
      int nt = rem >> 6, ln = rem & 63;
      int c  = nt * 16 + (ln & 15);
      int sl = tile * 32 + (ln >> 4) * 8;
      s8v v = *(const s8v*)&Vl[c * 72 + sl];
      *(s8v*)&vf[(((size_t)(bid * 2 + tile) * 16 + nt) * 64 + ln) * 8] = v;
    }
  } else {                                       // Q: row-major, pre-scaled, swizzled
    const u16* W = Wt;                           // Wq^T
    f4v acc[16];
    #pragma unroll
    for (int nt = 0; nt < 16; nt++) acc[nt] = (f4v){0.f, 0.f, 0.f, 0.f};
    #pragma unroll
    for (int ks = 0; ks < 8; ks++) {
      #pragma unroll
      for (int nt = 0; nt < 16; nt++) {
        s8v bfr = *(const s8v*)(W + (nt * 16 + l16) * DIM + ks * 32 + quad * 8);
        acc[nt] = MFMA16(a[ks], bfr, acc[nt]);
      }
    }
    #pragma unroll
    for (int nt = 0; nt < 16; nt++) {
      float bb = bq[nt * 16 + l16];
      #pragma unroll
      for (int r = 0; r < 4; r++)
        Kl[(wave * 16 + quad * 4 + r) * 264 + nt * 16 + l16] =
            f2bf((acc[nt][r] + bb) * 0.0625f);
    }
    __syncthreads();
    #pragma unroll
    for (int i = 0; i < 8; i++) {                // 2048 chunks, 8/thread
      int o = tid + i * 256;
      int row = o >> 5, c8 = (o & 31) * 8;
      s8v v = *(const s8v*)&Kl[row * 264 + c8];
      int colp = (c8 + ((row & 31) << 3)) & 255; // bank swizzle (global row ≡ row mod 32)
      *(s8v*)&qf[(size_t)(bid * 64 + row) * 256 + colp] = v;
    }
  }
}

// ---------- kernel 3 v8: flash attn, 16-wave blocks, 128-reg target ----------
// r7 LESSON: every structure plateaued at 104-122us with both pipes ~14% and
// ~70% dead cycles: latency-bound at the 192-reg -> 2-waves/SIMD ceiling.
// FIX: regs <= 128 total (o[8]=32 AGPR, qa read from LDS, Q pre-projected by
// proj_kernel) -> 4 waves/SIMD. 1024-thread blocks: 16 waves = 8 slabs x
// 2 col-halves share each 32-kv K/V tile (S duplicated per half; PV halved).
// Separate KVa/KVb + paired loop (chunk sizes always %4==0) so the compiler
// can prove DMA/read disjointness -> no mid-body vmcnt stalls.
__global__ __launch_bounds__(1024, 4) void attn_kernel(
    const u16* __restrict__ qf, const u16* __restrict__ kf, const u16* __restrict__ vf,
    float* __restrict__ Opart, float* __restrict__ lpart, float* __restrict__ out) {
  alignas(16) __shared__ u16 Qs[32768];           // 64 KB: 128 rows x 256 (swizzled)
  alignas(16) __shared__ u16 KVa[16384];          // 32 KB: K 16KB | V 16KB
  alignas(16) __shared__ u16 KVb[16384];          // 32 KB
  alignas(16) __shared__ u16 Ps[16 * 640];        // 20 KB, per-wave, stride 40
  __shared__ int taskS;

  int bid = blockIdx.x, b = bid & 3;              // batch <-> XCD-pair affinity
  int tid = threadIdx.x;
  int w = tid >> 6, lane = tid & 63, quad = lane >> 4, l16 = lane & 15;
  int s = w >> 1, h = w & 1;                      // slab 0..7, col-half 0..1

  const u16* qfb = qf + (size_t)b * T_SEQ * DIM;
  const u16* kfb = kf + (size_t)b * 128 * 8192;
  const u16* vfb = vf + (size_t)b * 128 * 8192;

  int qrow = (s << 4) + l16;                      // Qs row for qa reads
  int qbase = qrow << 8;
  int qrot = (qrow & 31) << 3;

  for (;;) {
    if (tid == 0) taskS = atomicAdd(&g_cnt[b], 1);
    __syncthreads();                              // also orders prev-task LDS reads
    int t = taskS;
    if (t >= 80) break;
    // size-descending enumeration over (q 128-row tile, c 32-kv chunk)
    int q, c;
    if (t < 8)        { q = 24 + t;        c = 0; }
    else if (t < 16)  { q = 24 + (t - 8);  c = 1; }
    else if (t < 24)  { q = 24 + (t - 16); c = 2; }
    else if (t == 24) { q = 31;            c = 3; }
    else if (t < 33)  { q = 16 + (t - 25); c = 0; }
    else if (t < 41)  { q = 16 + (t - 33); c = 1; }
    else if (t == 41) { q = 23;            c = 2; }
    else if (t < 50)  { q = 8 + (t - 42);  c = 0; }
    else if (t == 50) { q = 15;            c = 1; }
    else if (t == 51) { q = 7;             c = 0; }
    else { int u = t - 52, sz = u >> 2, band = u & 3;
           if (band == 0)      { q = 6 - sz;  c = 0; }
           else if (band == 1) { q = 14 - sz; c = 1; }
           else if (band == 2) { q = 22 - sz; c = 2; }
           else                { q = 30 - sz; c = 3; } }
    int row0 = q * 128;
    int n = 4 * q + 4;                            // causal kv-tile count
    int lo = c * 32, hi = min(n, lo + 32);        // chunk (size %4 == 0, >= 4)
    int nch = (q + 8) >> 3;                       // chunks for this tile (1..4)

    // ---- DMA Q tile (64 KB) + first KV tile into LDS (zero registers) ----
    {
      const u16* qsrc = qfb + ((size_t)row0 << 8) + (w << 11) + (lane << 3);
      u16* qdst = &Qs[w << 11];
      #pragma unroll
      for (int i = 0; i < 4; i++) gll16(qsrc + (i << 9), qdst + (i << 9));
      const u16* kt = kfb + ((size_t)lo << 13);
      const u16* vt = vfb + ((size_t)lo << 13);
      gll16(kt + (w << 9) + (lane << 3), &KVa[w << 9]);
      gll16(vt + (w << 9) + (lane << 3), &KVa[8192 + (w << 9)]);
    }
    __syncthreads();                              // drains all DMAs

    int rowBase = row0 + (s << 4);
    f4v o[8];
    #pragma unroll
    for (int nt = 0; nt < 8; nt++) o[nt] = (f4v){0.f, 0.f, 0.f, 0.f};
    float lrow[4] = {0.f, 0.f, 0.f, 0.f};

    auto iter_body = [&](const u16* buf, int kvi) {
      // S = Q K^T (full 32 kv cols; duplicated across the 2 half-waves)
      f4v c0 = (f4v){0.f, 0.f, 0.f, 0.f}, c1 = (f4v){0.f, 0.f, 0.f, 0.f};
      #pragma unroll
      for (int ks = 0; ks < 8; ks++) {
        s8v qa = *(const s8v*)&Qs[qbase + ((ks * 32 + (quad << 3) + qrot) & 255)];
        s8v k0 = *(const s8v*)&buf[(ks << 9) + (lane << 3)];
        s8v k1 = *(const s8v*)&buf[((8 + ks) << 9) + (lane << 3)];
        c0 = MFMA16(qa, k0, c0);
        c1 = MFMA16(qa, k1, c1);
      }
      int s0 = kvi * 32 + l16;
      #pragma unroll
      for (int r = 0; r < 4; r++) {
        int tq = rowBase + (quad << 2) + r;
        float v0 = (s0 > tq)      ? -1e30f : c0[r];
        float v1 = (s0 + 16 > tq) ? -1e30f : c1[r];
        float p0 = __expf(v0);
        float p1 = __expf(v1);
        Ps[w * 640 + ((quad << 2) + r) * 40 + l16]      = f2bf(p0);
        Ps[w * 640 + ((quad << 2) + r) * 40 + 16 + l16] = f2bf(p1);
        lrow[r] += p0 + p1;
      }
      FENCE_LGKM();                               // Ps write->read (same wave)
      s8v pa = *(const s8v*)&Ps[w * 640 + l16 * 40 + (quad << 3)];
      #pragma unroll
      for (int nt = 0; nt < 8; nt++) {
        s8v vfr = *(const s8v*)&buf[8192 + (((h << 3) + nt) << 9) + (lane << 3)];
        o[nt] = MFMA16(pa, vfr, o[nt]);
      }
    };

    #pragma unroll 1
    for (int kv = lo; kv < hi; kv += 2) {
      {                                           // prefetch kv+1 -> KVb (always valid)
        const u16* kt = kfb + ((size_t)(kv + 1) << 13);
        const u16* vt = vfb + ((size_t)(kv + 1) << 13);
        gll16(kt + (w << 9) + (lane << 3), &KVb[w << 9]);
        gll16(vt + (w << 9) + (lane << 3), &KVb[8192 + (w << 9)]);
      }
      iter_body(KVa, kv);
      __syncthreads();                            // KVb ready, KVa free
      if (kv + 2 < hi) {                          // prefetch kv+2 -> KVa
        const u16* kt = kfb + ((size_t)(kv + 2) << 13);
        const u16* vt = vfb + ((size_t)(kv + 2) << 13);
        gll16(kt + (w << 9) + (lane << 3), &KVa[w << 9]);
        gll16(vt + (w << 9) + (lane << 3), &KVa[8192 + (w << 9)]);
      }
      iter_body(KVb, kv + 1);
      __syncthreads();                            // KVa ready, KVb free
    }

    // ---- epilogue: row-sum reduce (full sum: S was duplicated) ----
    #pragma unroll
    for (int r = 0; r < 4; r++) {
      #pragma unroll
      for (int d = 1; d < 16; d <<= 1) lrow[r] += __shfl_xor(lrow[r], d);
    }

    if (nch == 1) {                               // whole kv range done: store
      float inv[4];
      #pragma unroll
      for (int r = 0; r < 4; r++) inv[r] = 1.0f / lrow[r];
      #pragma unroll
      for (int nt = 0; nt < 8; nt++) {
        #pragma unroll
        for (int r = 0; r < 4; r++)
          out[(size_t)(b * T_SEQ + rowBase + (quad << 2) + r) * DIM +
              ((h * 8 + nt) * 16 + l16)] = o[nt][r] * inv[r];
      }
    } else {                                      // fp32 partial to compact slot
      int slotB = (q < 16) ? (q - 8) * 2
                : (q < 24) ? 16 + (q - 16) * 3
                           : 40 + (q - 24) * 4;
      int slot = b * 72 + slotB + c;
      float* Op = Opart + ((size_t)slot << 15);   // 128*256 floats per slot
      #pragma unroll
      for (int nt = 0; nt < 8; nt++) {
        #pragma unroll
        for (int r = 0; r < 4; r++)
          Op[((s << 4) + (quad << 2) + r) * 256 + (h * 8 + nt) * 16 + l16] = o[nt][r];
      }
      if (h == 0 && l16 == 0) {
        #pragma unroll
        for (int r = 0; r < 4; r++)
          lpart[slot * 128 + (s << 4) + (quad << 2) + r] = lrow[r];
      }
    }
  }
}

// ---------- kernel 4: combine partials for multi-chunk tiles (q >= 8) -----
// grid 768 = 4 b x 24 q x 8 row-groups; block 256 (thread = column).
__global__ void combine_kernel(const float* __restrict__ Opart,
                               const float* __restrict__ lpart,
                               float* __restrict__ out) {
  int blk = blockIdx.x;
  int b = blk & 3;
  int rest = blk >> 2;                            // 0..191
  int q = 8 + (rest >> 3);
  int g = rest & 7;                               // 16-row group
  int col = threadIdx.x;
  int nch = (q + 8) >> 3;                         // 2,3,4
  int slotB = (q < 16) ? (q - 8) * 2
            : (q < 24) ? 16 + (q - 16) * 3
                       : 40 + (q - 24) * 4;
  int slot0 = b * 72 + slotB;
  #pragma unroll 4
  for (int i = 0; i < 16; i++) {
    int rt = g * 16 + i;                          // row within 128-row tile
    float acc = 0.f, ls = 0.f;
    for (int c = 0; c < nch; c++) {
      acc += Opart[(((size_t)(slot0 + c)) << 15) + rt * 256 + col];
      ls  += lpart[(slot0 + c) * 128 + rt];
    }
    out[(size_t)(b * T_SEQ + q * 128 + rt) * DIM + col] = acc / ls;
  }
}

extern "C" void kernel_launch(void* const* d_in, const int* in_sizes, int n_in,
                              void* d_out, int out_size, void* d_ws, size_t ws_size,
                              hipStream_t stream) {
  const float* x  = (const float*)d_in[0];
  const float* Wq = (const float*)d_in[1];
  const float* bq = (const float*)d_in[2];
  const float* Wk = (const float*)d_in[3];
  const float* bk = (const float*)d_in[4];
  const float* Wv = (const float*)d_in[5];
  const float* bv = (const float*)d_in[6];

  const size_t NTD = (size_t)NBATCH * T_SEQ * DIM;             // 4,194,304 elems
  const size_t WT_ELEMS = (size_t)3 * DIM * DIM;               //   196,608 elems
  const size_t NSLOT = 288;                                    // partial slots (128x256)
  const size_t REQ_BYTES = (WT_ELEMS + 3 * NTD) * sizeof(u16)  // 25,559,040
                         + NSLOT * 32768 * sizeof(float)       // 37,748,736 Opart
                         + NSLOT * 128 * sizeof(float);        //    147,456 lpart

  if (ws_size < REQ_BYTES) {
    float val = (float)(ws_size >> 20);   // diagnostic: absmax encodes ws MiB
    diag_fill_kernel<<<(out_size + 255) / 256, 256, 0, stream>>>((float*)d_out, val, out_size);
    return;
  }

  u16* ws = (u16*)d_ws;
  u16* WT = ws;                    // [0]=Wq^T [1]=Wk^T [2]=Wv^T, 384 KiB
  u16* Kf = ws + WT_ELEMS;         // 8 MiB, frag-major K tiles
  u16* Vf = Kf + NTD;              // 8 MiB, frag-major V^T tiles
  u16* Qf = Vf + NTD;              // 8 MiB, row-major swizzled Q (pre-scaled)
  float* Opart = (float*)(Qf + NTD);               // 36 MiB fp32 partial O
  float* lpart = Opart + NSLOT * 32768;            // 144 KiB fp32 partial l

  wtrans_kernel<<<dim3(8, 8, 3), dim3(32, 8, 1), 0, stream>>>(Wq, Wk, Wv, WT);
  proj_kernel<<<dim3(256, 3, 1), dim3(256, 1, 1), 0, stream>>>(x, WT, bq, bk, bv, Qf, Kf, Vf);
  attn_kernel<<<dim3(256, 1, 1), dim3(1024, 1, 1), 0, stream>>>(Qf, Kf, Vf,
                                                                Opart, lpart, (float*)d_out);
  combine_kernel<<<dim3(768, 1, 1), dim3(256, 1, 1), 0, stream>>>(Opart, lpart, (float*)d_out);
}

// Round 9
// 212.198 us; speedup vs baseline: 1.9582x; 1.0741x over previous
//
#include <hip/hip_runtime.h>
#include <hip/hip_bf16.h>

#define T_SEQ 4096
#define DIM   256
#define NBATCH 4

typedef short s8v __attribute__((ext_vector_type(8)));   // 8 bf16 (A/B frag)
typedef float f4v __attribute__((ext_vector_type(4)));   // 4 fp32 (C/D frag)
typedef unsigned short u16;

#define MFMA16(a,b,c) __builtin_amdgcn_mfma_f32_16x16x32_bf16(a,b,c,0,0,0)
#define FENCE_LGKM() asm volatile("s_waitcnt lgkmcnt(0)" ::: "memory")

// dynamic task counters, one per batch; zeroed by wtrans_kernel each launch
__device__ int g_cnt[4];

static __device__ __forceinline__ u16 f2bf(float f) {
  union { float f; unsigned int u; } c; c.f = f;
  unsigned int u = c.u;
  unsigned int r = (u + 0x7fffu + ((u >> 16) & 1u)) >> 16;   // RNE
  return (u16)r;
}

static __device__ __forceinline__ s8v pack8(const float* p) {
  float4 a = *(const float4*)p;
  float4 b = *(const float4*)(p + 4);
  s8v r;
  r[0] = (short)f2bf(a.x); r[1] = (short)f2bf(a.y);
  r[2] = (short)f2bf(a.z); r[3] = (short)f2bf(a.w);
  r[4] = (short)f2bf(b.x); r[5] = (short)f2bf(b.y);
  r[6] = (short)f2bf(b.z); r[7] = (short)f2bf(b.w);
  return r;
}

// async global->LDS DMA, 16B/lane: lds dest is WAVE-UNIFORM base (+lane*16 by HW)
static __device__ __forceinline__ void gll16(const u16* g, u16* l) {
  __builtin_amdgcn_global_load_lds(
      (const __attribute__((address_space(1))) unsigned int*)g,
      (__attribute__((address_space(3))) unsigned int*)l, 16, 0, 0);
}

// ---------- diagnostic fallback (fp32 out) ----------
__global__ void diag_fill_kernel(float* __restrict__ out, float val, int n) {
  int i = blockIdx.x * blockDim.x + threadIdx.x;
  if (i < n) out[i] = val;
}

// ---------- kernel 1: Wt[n][k] = bf16(W[k][n]) ----------
__global__ void wtrans_kernel(const float* __restrict__ Wq, const float* __restrict__ Wk,
                              const float* __restrict__ Wv, u16* __restrict__ Wt) {
  if (blockIdx.x == 0 && blockIdx.y == 0 && blockIdx.z == 0 &&
      threadIdx.y == 0 && threadIdx.x < 4)
    g_cnt[threadIdx.x] = 0;                    // reset attn task queues (stream-ordered)
  __shared__ float tile[32][33];
  int m = blockIdx.z;
  const float* W = (m == 0) ? Wq : ((m == 1) ? Wk : Wv);
  int bx = blockIdx.x * 32, by = blockIdx.y * 32;
  int x = threadIdx.x, y = threadIdx.y;          // block (32,8)
  #pragma unroll
  for (int i = 0; i < 32; i += 8) tile[y + i][x] = W[(by + y + i) * DIM + bx + x];
  __syncthreads();
  u16* o = Wt + m * DIM * DIM;
  #pragma unroll
  for (int i = 0; i < 32; i += 8) o[(bx + y + i) * DIM + by + x] = f2bf(tile[x][y + i]);
}

// ---------- kernel 2: Q / K / V projections -> FRAGMENT-MAJOR tiles ------
// grid (256, 3): y=0 -> K, y=1 -> V^T, y=2 -> Q (SAME frag-major format as K,
// pre-scaled 1/16). Frag f of a 32-row tile: elem(seq,dim): seq = tile*32 +
// (f>>3)*16 + (ln&15), dim = (f&7)*32 + (ln>>4)*8 + j.
__global__ __launch_bounds__(256) void proj_kernel(
    const float* __restrict__ x, const u16* __restrict__ Wt,
    const float* __restrict__ bq, const float* __restrict__ bk, const float* __restrict__ bv,
    u16* __restrict__ qf, u16* __restrict__ kf, u16* __restrict__ vf) {
  alignas(16) __shared__ u16 Kl[64 * 264];       // rows, pad 256->264
  alignas(16) __shared__ u16 Vl[256 * 72];       // V^T [c][t_local], pad 64->72

  int bid = blockIdx.x;
  int which = blockIdx.y;                        // 0 = K, 1 = V, 2 = Q
  int tid  = threadIdx.x;
  int wave = tid >> 6, lane = tid & 63, quad = lane >> 4, l16 = lane & 15;
  int row0 = bid * 64 + wave * 16;

  s8v a[8];
  const float* xp = x + (size_t)(row0 + l16) * DIM + quad * 8;
  #pragma unroll
  for (int ks = 0; ks < 8; ks++) a[ks] = pack8(xp + ks * 32);

  if (which == 0) {
    const u16* W = Wt + DIM * DIM;               // Wk^T
    f4v acc[16];
    #pragma unroll
    for (int nt = 0; nt < 16; nt++) acc[nt] = (f4v){0.f, 0.f, 0.f, 0.f};
    #pragma unroll
    for (int ks = 0; ks < 8; ks++) {
      #pragma unroll
      for (int nt = 0; nt < 16; nt++) {
        s8v bfr = *(const s8v*)(W + (nt * 16 + l16) * DIM + ks * 32 + quad * 8);
        acc[nt] = MFMA16(a[ks], bfr, acc[nt]);
      }
    }
    #pragma unroll
    for (int nt = 0; nt < 16; nt++) {
      float bb = bk[nt * 16 + l16];
      #pragma unroll
      for (int r = 0; r < 4; r++)
        Kl[(wave * 16 + quad * 4 + r) * 264 + nt * 16 + l16] = f2bf(acc[nt][r] + bb);
    }
    __syncthreads();
    #pragma unroll
    for (int i = 0; i < 8; i++) {                // 2048 chunks, 8/thread
      int o = tid + i * 256;
      int tile = o >> 10, rem = o & 1023;
      int f = rem >> 6, ln = rem & 63;
      int sl = tile * 32 + (f >> 3) * 16 + (ln & 15);
      int c  = (f & 7) * 32 + (ln >> 4) * 8;
      s8v v = *(const s8v*)&Kl[sl * 264 + c];
      *(s8v*)&kf[(((size_t)(bid * 2 + tile) * 16 + f) * 64 + ln) * 8] = v;
    }
  } else if (which == 1) {
    const u16* W = Wt + 2 * DIM * DIM;           // Wv^T
    f4v acc[16];
    #pragma unroll
    for (int nt = 0; nt < 16; nt++) acc[nt] = (f4v){0.f, 0.f, 0.f, 0.f};
    #pragma unroll
    for (int ks = 0; ks < 8; ks++) {
      #pragma unroll
      for (int nt = 0; nt < 16; nt++) {
        s8v bfr = *(const s8v*)(W + (nt * 16 + l16) * DIM + ks * 32 + quad * 8);
        acc[nt] = MFMA16(a[ks], bfr, acc[nt]);
      }
    }
    #pragma unroll
    for (int nt = 0; nt < 16; nt++) {
      float bb = bv[nt * 16 + l16];
      union { u16 h[4]; uint2 v2; } pk;
      #pragma unroll
      for (int r = 0; r < 4; r++) pk.h[r] = f2bf(acc[nt][r] + bb);
      *(uint2*)&Vl[(nt * 16 + l16) * 72 + wave * 16 + quad * 4] = pk.v2;
    }
    __syncthreads();
    #pragma unroll
    for (int i = 0; i < 8; i++) {                // 2048 chunks, 8/thread
      int o = tid + i * 256;
      int tile = o >> 10, rem = o & 1023;
      int nt = rem >> 6, ln = rem & 63;
      int c  = nt * 16 + (ln & 15);
      int sl = tile * 32 + (ln >> 4) * 8;
      s8v v = *(const s8v*)&Vl[c * 72 + sl];
      *(s8v*)&vf[(((size_t)(bid * 2 + tile) * 16 + nt) * 64 + ln) * 8] = v;
    }
  } else {                                       // Q: frag-major like K, pre-scaled
    const u16* W = Wt;                           // Wq^T
    f4v acc[16];
    #pragma unroll
    for (int nt = 0; nt < 16; nt++) acc[nt] = (f4v){0.f, 0.f, 0.f, 0.f};
    #pragma unroll
    for (int ks = 0; ks < 8; ks++) {
      #pragma unroll
      for (int nt = 0; nt < 16; nt++) {
        s8v bfr = *(const s8v*)(W + (nt * 16 + l16) * DIM + ks * 32 + quad * 8);
        acc[nt] = MFMA16(a[ks], bfr, acc[nt]);
      }
    }
    #pragma unroll
    for (int nt = 0; nt < 16; nt++) {
      float bb = bq[nt * 16 + l16];
      #pragma unroll
      for (int r = 0; r < 4; r++)
        Kl[(wave * 16 + quad * 4 + r) * 264 + nt * 16 + l16] =
            f2bf((acc[nt][r] + bb) * 0.0625f);   // pre-scale 1/sqrt(256)
    }
    __syncthreads();
    #pragma unroll
    for (int i = 0; i < 8; i++) {                // 2048 chunks, 8/thread
      int o = tid + i * 256;
      int tile = o >> 10, rem = o & 1023;
      int f = rem >> 6, ln = rem & 63;
      int sl = tile * 32 + (f >> 3) * 16 + (ln & 15);
      int c  = (f & 7) * 32 + (ln >> 4) * 8;
      s8v v = *(const s8v*)&Kl[sl * 264 + c];
      *(s8v*)&qf[(((size_t)(bid * 2 + tile) * 16 + f) * 64 + ln) * 8] = v;
    }
  }
}

// ---------- kernel 3 v9: flash attn, LDS-diet (Q in regs, S kv-split) --------
// r8 DIAGNOSIS: LDS-BW-bound. 35 KB LDS reads/wave-iter x 16 waves = 560 KB
// per block-iter -> 6600 cyc at 85 B/cyc = the measured 6400 cyc/iter; caps
// MFMA at ~24% (measured). v9 cuts to ~17.5 KB/wave-iter:
//  - Q A-frags in REGISTERS (qa[8]=32 VGPR), loaded once per task from
//    frag-major Qf (coalesced, L2-resident). -8 KB/iter, kills Qs array.
//  - S computed once: wave (slab,h) does its 16-kv half (8 MFMA, K-read 8 KB),
//    halves exchange P via per-slab Ps with lgkmcnt(0)+raw s_barrier (no
//    vmcnt drain -> prefetch DMA stays in flight). -8 KB/iter K, -4 exp.
// Chunking/slots/combine identical to r8 (32-kv chunks; 16-chunks would
// explode partial traffic by +70 MB).
__global__ __launch_bounds__(1024, 4) void attn_kernel(
    const u16* __restrict__ qf, const u16* __restrict__ kf, const u16* __restrict__ vf,
    float* __restrict__ Opart, float* __restrict__ lpart, float* __restrict__ out) {
  alignas(16) __shared__ u16 KVa[16384];          // 32 KB: K 16KB | V 16KB
  alignas(16) __shared__ u16 KVb[16384];          // 32 KB
  alignas(16) __shared__ u16 Ps[8 * 640];         // 10 KB, per-SLAB (2 waves), stride 40
  __shared__ float lbuf[8][2][16];                // per-slab, per-half row sums
  __shared__ int taskS;

  int bid = blockIdx.x, b = bid & 3;              // batch <-> XCD-pair affinity
  int tid = threadIdx.x;
  int w = tid >> 6, lane = tid & 63, quad = lane >> 4, l16 = lane & 15;
  int s = w >> 1, h = w & 1;                      // slab 0..7, kv/col-half 0..1

  const u16* qfb = qf + (size_t)b * 128 * 8192;
  const u16* kfb = kf + (size_t)b * 128 * 8192;
  const u16* vfb = vf + (size_t)b * 128 * 8192;

  for (;;) {
    if (tid == 0) taskS = atomicAdd(&g_cnt[b], 1);
    __syncthreads();                              // also orders prev-task LDS reads
    int t = taskS;
    if (t >= 80) break;
    // size-descending enumeration over (q 128-row tile, c 32-kv chunk)
    int q, c;
    if (t < 8)        { q = 24 + t;        c = 0; }
    else if (t < 16)  { q = 24 + (t - 8);  c = 1; }
    else if (t < 24)  { q = 24 + (t - 16); c = 2; }
    else if (t == 24) { q = 31;            c = 3; }
    else if (t < 33)  { q = 16 + (t - 25); c = 0; }
    else if (t < 41)  { q = 16 + (t - 33); c = 1; }
    else if (t == 41) { q = 23;            c = 2; }
    else if (t < 50)  { q = 8 + (t - 42);  c = 0; }
    else if (t == 50) { q = 15;            c = 1; }
    else if (t == 51) { q = 7;             c = 0; }
    else { int u = t - 52, sz = u >> 2, band = u & 3;
           if (band == 0)      { q = 6 - sz;  c = 0; }
           else if (band == 1) { q = 14 - sz; c = 1; }
           else if (band == 2) { q = 22 - sz; c = 2; }
           else                { q = 30 - sz; c = 3; } }
    int row0 = q * 128;
    int n = 4 * q + 4;                            // causal kv-tile count
    int lo = c * 32, hi = min(n, lo + 32);        // chunk (size %4 == 0, >= 4)
    int nch = (q + 8) >> 3;                       // chunks for this tile (1..4)

    // ---- Q A-frags -> registers (once per task; frag-major, coalesced) ----
    s8v qa[8];
    {
      const u16* qt = qfb + (((size_t)(q * 4 + (s >> 1)) * 16 + (s & 1) * 8) * 64) * 8;
      #pragma unroll
      for (int ks = 0; ks < 8; ks++) qa[ks] = *(const s8v*)(qt + (ks * 64 + lane) * 8);
    }

    // ---- prologue: DMA first KV tile into KVa (zero registers) ----
    {
      const u16* kt = kfb + ((size_t)lo << 13);
      const u16* vt = vfb + ((size_t)lo << 13);
      gll16(kt + (w << 9) + (lane << 3), &KVa[w << 9]);
      gll16(vt + (w << 9) + (lane << 3), &KVa[8192 + (w << 9)]);
    }
    __syncthreads();                              // drains DMA

    int rowBase = row0 + (s << 4);
    f4v o[8];
    #pragma unroll
    for (int nt = 0; nt < 8; nt++) o[nt] = (f4v){0.f, 0.f, 0.f, 0.f};
    float lrow[4] = {0.f, 0.f, 0.f, 0.f};

    auto iter_body = [&](const u16* buf, int kvi) {
      // S half: wave h computes S for its slab x 16 kv cols (h*16..h*16+15)
      f4v cc = (f4v){0.f, 0.f, 0.f, 0.f};
      #pragma unroll
      for (int ks = 0; ks < 8; ks++) {
        s8v kfr = *(const s8v*)&buf[(((h << 3) + ks) << 9) + (lane << 3)];
        cc = MFMA16(qa[ks], kfr, cc);
      }
      int s0 = kvi * 32 + (h << 4) + l16;
      #pragma unroll
      for (int r = 0; r < 4; r++) {
        int tq = rowBase + (quad << 2) + r;
        float p = __expf((s0 > tq) ? -1e30f : cc[r]);
        Ps[s * 640 + ((quad << 2) + r) * 40 + (h << 4) + l16] = f2bf(p);
        lrow[r] += p;
      }
      // P exchange: own writes drained (lgkm), partner sync via RAW s_barrier
      // (no vmcnt drain -> next-tile DMA stays in flight across it).
      FENCE_LGKM();
      __builtin_amdgcn_sched_barrier(0);
      __builtin_amdgcn_s_barrier();
      __builtin_amdgcn_sched_barrier(0);
      s8v pa = *(const s8v*)&Ps[s * 640 + l16 * 40 + (quad << 3)];
      #pragma unroll
      for (int nt = 0; nt < 8; nt++) {
        s8v vfr = *(const s8v*)&buf[8192 + (((h << 3) + nt) << 9) + (lane << 3)];
        o[nt] = MFMA16(pa, vfr, o[nt]);
      }
    };

    #pragma unroll 1
    for (int kv = lo; kv < hi; kv += 2) {
      {                                           // prefetch kv+1 -> KVb (always valid)
        const u16* kt = kfb + ((size_t)(kv + 1) << 13);
        const u16* vt = vfb + ((size_t)(kv + 1) << 13);
        gll16(kt + (w << 9) + (lane << 3), &KVb[w << 9]);
        gll16(vt + (w << 9) + (lane << 3), &KVb[8192 + (w << 9)]);
      }
      iter_body(KVa, kv);
      __syncthreads();                            // KVb ready, KVa free, Ps consumed
      if (kv + 2 < hi) {                          // prefetch kv+2 -> KVa
        const u16* kt = kfb + ((size_t)(kv + 2) << 13);
        const u16* vt = vfb + ((size_t)(kv + 2) << 13);
        gll16(kt + (w << 9) + (lane << 3), &KVa[w << 9]);
        gll16(vt + (w << 9) + (lane << 3), &KVa[8192 + (w << 9)]);
      }
      iter_body(KVb, kv + 1);
      __syncthreads();                            // KVa ready, KVb free
    }

    // ---- epilogue: per-half row sums -> combine across halves via lbuf ----
    #pragma unroll
    for (int r = 0; r < 4; r++) {
      #pragma unroll
      for (int d = 1; d < 16; d <<= 1) lrow[r] += __shfl_xor(lrow[r], d);
    }
    if (l16 == 0) {
      #pragma unroll
      for (int r = 0; r < 4; r++) lbuf[s][h][(quad << 2) + r] = lrow[r];
    }
    __syncthreads();                              // lbuf ready for both halves

    if (nch == 1) {                               // whole kv range done: store
      #pragma unroll
      for (int nt = 0; nt < 8; nt++) {
        #pragma unroll
        for (int r = 0; r < 4; r++) {
          float ls = lbuf[s][0][(quad << 2) + r] + lbuf[s][1][(quad << 2) + r];
          out[(size_t)(b * T_SEQ + rowBase + (quad << 2) + r) * DIM +
              ((h * 8 + nt) * 16 + l16)] = o[nt][r] / ls;
        }
      }
    } else {                                      // fp32 partial to compact slot
      int slotB = (q < 16) ? (q - 8) * 2
                : (q < 24) ? 16 + (q - 16) * 3
                           : 40 + (q - 24) * 4;
      int slot = b * 72 + slotB + c;
      float* Op = Opart + ((size_t)slot << 15);   // 128*256 floats per slot
      #pragma unroll
      for (int nt = 0; nt < 8; nt++) {
        #pragma unroll
        for (int r = 0; r < 4; r++)
          Op[((s << 4) + (quad << 2) + r) * 256 + (h * 8 + nt) * 16 + l16] = o[nt][r];
      }
      if (h == 0 && l16 == 0) {
        #pragma unroll
        for (int r = 0; r < 4; r++)
          lpart[slot * 128 + (s << 4) + (quad << 2) + r] =
              lbuf[s][0][(quad << 2) + r] + lbuf[s][1][(quad << 2) + r];
      }
    }
  }
}

// ---------- kernel 4: combine partials for multi-chunk tiles (q >= 8) -----
// grid 768 = 4 b x 24 q x 8 row-groups; block 256 (thread = column).
__global__ void combine_kernel(const float* __restrict__ Opart,
                               const float* __restrict__ lpart,
                               float* __restrict__ out) {
  int blk = blockIdx.x;
  int b = blk & 3;
  int rest = blk >> 2;                            // 0..191
  int q = 8 + (rest >> 3);
  int g = rest & 7;                               // 16-row group
  int col = threadIdx.x;
  int nch = (q + 8) >> 3;                         // 2,3,4
  int slotB = (q < 16) ? (q - 8) * 2
            : (q < 24) ? 16 + (q - 16) * 3
                       : 40 + (q - 24) * 4;
  int slot0 = b * 72 + slotB;
  #pragma unroll 4
  for (int i = 0; i < 16; i++) {
    int rt = g * 16 + i;                          // row within 128-row tile
    float acc = 0.f, ls = 0.f;
    for (int c = 0; c < nch; c++) {
      acc += Opart[(((size_t)(slot0 + c)) << 15) + rt * 256 + col];
      ls  += lpart[(slot0 + c) * 128 + rt];
    }
    out[(size_t)(b * T_SEQ + q * 128 + rt) * DIM + col] = acc / ls;
  }
}

extern "C" void kernel_launch(void* const* d_in, const int* in_sizes, int n_in,
                              void* d_out, int out_size, void* d_ws, size_t ws_size,
                              hipStream_t stream) {
  const float* x  = (const float*)d_in[0];
  const float* Wq = (const float*)d_in[1];
  const float* bq = (const float*)d_in[2];
  const float* Wk = (const float*)d_in[3];
  const float* bk = (const float*)d_in[4];
  const float* Wv = (const float*)d_in[5];
  const float* bv = (const float*)d_in[6];

  const size_t NTD = (size_t)NBATCH * T_SEQ * DIM;             // 4,194,304 elems
  const size_t WT_ELEMS = (size_t)3 * DIM * DIM;               //   196,608 elems
  const size_t NSLOT = 288;                                    // partial slots (128x256)
  const size_t REQ_BYTES = (WT_ELEMS + 3 * NTD) * sizeof(u16)  // 25,559,040
                         + NSLOT * 32768 * sizeof(float)       // 37,748,736 Opart
                         + NSLOT * 128 * sizeof(float);        //    147,456 lpart

  if (ws_size < REQ_BYTES) {
    float val = (float)(ws_size >> 20);   // diagnostic: absmax encodes ws MiB
    diag_fill_kernel<<<(out_size + 255) / 256, 256, 0, stream>>>((float*)d_out, val, out_size);
    return;
  }

  u16* ws = (u16*)d_ws;
  u16* WT = ws;                    // [0]=Wq^T [1]=Wk^T [2]=Wv^T, 384 KiB
  u16* Kf = ws + WT_ELEMS;         // 8 MiB, frag-major K tiles
  u16* Vf = Kf + NTD;              // 8 MiB, frag-major V^T tiles
  u16* Qf = Vf + NTD;              // 8 MiB, frag-major Q tiles (pre-scaled)
  float* Opart = (float*)(Qf + NTD);               // 36 MiB fp32 partial O
  float* lpart = Opart + NSLOT * 32768;            // 144 KiB fp32 partial l

  wtrans_kernel<<<dim3(8, 8, 3), dim3(32, 8, 1), 0, stream>>>(Wq, Wk, Wv, WT);
  proj_kernel<<<dim3(256, 3, 1), dim3(256, 1, 1), 0, stream>>>(x, WT, bq, bk, bv, Qf, Kf, Vf);
  attn_kernel<<<dim3(256, 1, 1), dim3(1024, 1, 1), 0, stream>>>(Qf, Kf, Vf,
                                                                Opart, lpart, (float*)d_out);
  combine_kernel<<<dim3(768, 1, 1), dim3(256, 1, 1), 0, stream>>>(Opart, lpart, (float*)d_out);
}